// Round 3
// baseline (156.919 us; speedup 1.0000x reference)
//
#include <hip/hip_runtime.h>
#include <hip/hip_fp16.h>

#define NQ 12
#define DEPTH 8
#define NCLASS 10
#define BATCH 4096
#define LSTRIDE_H 72   // LDS row stride in HALVES (144 B, mult of 16 for b128; 36 dwords -> bank phase 4l)
#define WPB 2          // waves (= samples) per block; LDS = 2*64*72*2 = 18432 B -> 8 blocks/CU = 16 waves

// ---------------------------------------------------------------------------
// One wave per sample; statevector (4096 amps) lives in v[64] fp32 per lane.
// Frame A: qubit q in 0..5  <-> lane bit (5-q);  q in 6..11 <-> reg bit (11-q)
// Frame B: qubit q in 0..5  <-> reg  bit (5-q);  q in 6..11 <-> lane bit (11-q)
// Per layer:
//   RT1: LDS round-trip implementing (transpose ∘ CNOT_odd ∘ CNOT_even), A->B
//        src_lane = h(r) (compile-time), src_col = g(l) ^ (r&1 ? 0x30 : 0)
//   RY qubits 0..5   (reg-local in frame B, pure VALU)
//   RT2: plain transpose B->A
//   RY qubits 6..11  (reg-local in frame A, pure VALU)
// LDS buffer holds fp16 (RTNE both directions): halves footprint -> 2x occupancy.
// All DS ops are intra-wave (private region per wave, DS in-order) -> no barriers.
// ---------------------------------------------------------------------------

typedef __attribute__((ext_vector_type(8))) unsigned short ushort8;  // 16 B

__device__ constexpr int hfun(int r) {  // src lane for RT1 output reg r (CNOT index map)
    const int rb5 = (r >> 5) & 1, rb4 = (r >> 4) & 1, rb3 = (r >> 3) & 1;
    const int rb2 = (r >> 2) & 1, rb1 = (r >> 1) & 1, rb0 = r & 1;
    const int c0 = rb5;
    const int c1 = rb4 ^ rb5;
    const int c2 = rb3 ^ rb4;
    const int c3 = rb2 ^ rb3 ^ rb4;
    const int c4 = rb1 ^ rb2;
    const int c5 = rb0 ^ rb1 ^ rb2;
    return (c0 << 5) | (c1 << 4) | (c2 << 3) | (c3 << 2) | (c4 << 1) | c5;
}

__global__ __launch_bounds__(WPB * 64, 4) void vqc_kernel(const float* __restrict__ X,
                                                          const float* __restrict__ W,
                                                          float* __restrict__ out) {
    __shared__ __align__(16) unsigned short lds[WPB * 64 * LSTRIDE_H];

    const int lane   = threadIdx.x & 63;
    const int wid    = threadIdx.x >> 6;
    const int sample = blockIdx.x * WPB + wid;
    const int l      = lane;

    unsigned short* Wb   = &lds[wid * 64 * LSTRIDE_H];
    unsigned short* wrow = &Wb[l * LSTRIDE_H];        // row-major write base (16B aligned)
    // g(l): src column l-part for RT1 (CNOT chain on qubits 6..11 folded)
    const int G = l ^ (l >> 1) ^ ((l >> 2) & 5);
    const unsigned short* rG0 = &Wb[G];               // r even (q5=0)
    const unsigned short* rG1 = &Wb[G ^ 0x30];        // r odd  (q5=1): CNOT(5,6) column flip
    const unsigned short* rT2 = &Wb[l];               // RT2 read base

    // ---- data encoding: product state, frame A ----
    float cx[NQ], sx[NQ];
#pragma unroll
    for (int q = 0; q < NQ; ++q) {
        float ang = 0.5f * X[sample * NQ + q] + 0.78539816339744831f;
        __sincosf(ang, &sx[q], &cx[q]);
    }
    float P = 1.0f;
#pragma unroll
    for (int q = 0; q < 6; ++q) P *= ((l >> (5 - q)) & 1) ? sx[q] : cx[q];

    float v[64];
    v[0] = P * cx[11];
    v[1] = P * sx[11];
#pragma unroll
    for (int lvl = 1; lvl < 6; ++lvl) {
        const int q = 11 - lvl;
#pragma unroll
        for (int j = 0; j < (1 << 5); ++j) {
            if (j >= (1 << lvl)) continue;
            v[j + (1 << lvl)] = v[j] * sx[q];
            v[j]              = v[j] * cx[q];
        }
    }

    // ---- variational layers ----
#pragma unroll 1
    for (int k = 0; k < DEPTH; ++k) {
        // ---- RT1: frame A -> frame B with both CNOT groups folded (fp16 staging) ----
#pragma unroll
        for (int t = 0; t < 8; ++t) {
            ushort8 w;
#pragma unroll
            for (int i = 0; i < 8; ++i)
                w[i] = __half_as_ushort(__float2half(v[8 * t + i]));   // RTNE
            *(ushort8*)&wrow[8 * t] = w;
        }
#pragma unroll
        for (int r = 0; r < 64; ++r)
            v[r] = __half2float(__ushort_as_half(((r & 1) ? rG1 : rG0)[hfun(r) * LSTRIDE_H]));

        // ---- RY qubits 0..5 (frame B: qubit p <-> reg bit 5-p) ----
#pragma unroll
        for (int p = 0; p < 6; ++p) {
            float cw, sw;
            __sincosf(0.5f * W[k * NQ + p], &sw, &cw);
            const int m = 1 << (5 - p);
#pragma unroll
            for (int r = 0; r < 64; ++r) {
                if (!(r & m)) {
                    const int r1 = r | m;
                    const float a = v[r], b = v[r1];
                    v[r]  = cw * a - sw * b;
                    v[r1] = sw * a + cw * b;
                }
            }
        }

        // ---- RT2: plain transpose, frame B -> frame A (fp16 staging) ----
#pragma unroll
        for (int t = 0; t < 8; ++t) {
            ushort8 w;
#pragma unroll
            for (int i = 0; i < 8; ++i)
                w[i] = __half_as_ushort(__float2half(v[8 * t + i]));   // RTNE
            *(ushort8*)&wrow[8 * t] = w;
        }
#pragma unroll
        for (int j = 0; j < 64; ++j)
            v[j] = __half2float(__ushort_as_half(rT2[j * LSTRIDE_H]));

        // ---- RY qubits 6..11 (frame A: qubit p <-> reg bit 11-p) ----
#pragma unroll
        for (int p = 6; p < NQ; ++p) {
            float cw, sw;
            __sincosf(0.5f * W[k * NQ + p], &sw, &cw);
            const int m = 1 << (11 - p);
#pragma unroll
            for (int r = 0; r < 64; ++r) {
                if (!(r & m)) {
                    const int r1 = r | m;
                    const float a = v[r], b = v[r1];
                    v[r]  = cw * a - sw * b;
                    v[r1] = sw * a + cw * b;
                }
            }
        }
    }

    // ---- measurement: <Z_p> = P(bit p = 0) - P(bit p = 1), frame A ----
#pragma unroll
    for (int j = 0; j < 64; ++j) v[j] *= v[j];

    float c2[16];  // summed over reg bits 0,1
#pragma unroll
    for (int m = 0; m < 16; ++m)
        c2[m] = (v[4 * m] + v[4 * m + 1]) + (v[4 * m + 2] + v[4 * m + 3]);

    float S = 0.0f;
#pragma unroll
    for (int m = 0; m < 16; ++m) S += c2[m];

    float T[4];  // signed sum on reg bit t+2
#pragma unroll
    for (int t = 0; t < 4; ++t) {
        float acc = 0.0f;
#pragma unroll
        for (int m = 0; m < 16; ++m) acc += ((m >> t) & 1) ? -c2[m] : c2[m];
        T[t] = acc;
    }

    float o[NCLASS];
#pragma unroll
    for (int p = 0; p < 6; ++p) {   // qubit p on lane bit (5-p)
        float r = ((l >> (5 - p)) & 1) ? -S : S;
#pragma unroll
        for (int m = 0; m < 6; ++m) r += __shfl_xor(r, 1 << m, 64);
        o[p] = r;
    }
#pragma unroll
    for (int p = 6; p < 10; ++p) {  // qubit p on reg bit (11-p) -> T[9-p]
        float r = T[9 - p];
#pragma unroll
        for (int m = 0; m < 6; ++m) r += __shfl_xor(r, 1 << m, 64);
        o[p] = r;
    }

    if (lane == 0) {
#pragma unroll
        for (int p = 0; p < NCLASS; ++p) out[sample * NCLASS + p] = o[p];
    }
}

extern "C" void kernel_launch(void* const* d_in, const int* in_sizes, int n_in,
                              void* d_out, int out_size, void* d_ws, size_t ws_size,
                              hipStream_t stream) {
    const float* X = (const float*)d_in[0];
    const float* W = (const float*)d_in[1];
    float* out     = (float*)d_out;
    (void)in_sizes; (void)n_in; (void)out_size; (void)d_ws; (void)ws_size;

    dim3 grid(BATCH / WPB);
    dim3 block(WPB * 64);
    hipLaunchKernelGGL(vqc_kernel, grid, block, 0, stream, X, W, out);
}

// Round 4
// 130.291 us; speedup vs baseline: 1.2044x; 1.2044x over previous
//
#include <hip/hip_runtime.h>
#include <hip/hip_fp16.h>

#define NQ 12
#define DEPTH 8
#define NCLASS 10
#define BATCH 4096
#define LSTRIDE_H 72   // LDS row stride in HALVES (144 B, mult of 16 for b128)
#define WPB 2          // waves (= samples) per block; LDS = 2*64*72*2 = 18432 B -> 8 blocks/CU

// ---------------------------------------------------------------------------
// One wave per sample; statevector (4096 amps) lives in v[64] fp32 per lane.
// Frame A: qubit q in 0..5  <-> lane bit (5-q);  q in 6..11 <-> reg bit (11-q)
// Frame B: qubit q in 0..5  <-> reg  bit (5-q);  q in 6..11 <-> lane bit (11-q)
// Per layer:
//   RT1: LDS round-trip implementing (transpose ∘ CNOT_odd ∘ CNOT_even), A->B
//   RY qubits 0..5   (reg-local in frame B, packed-f32 VALU)
//   RT2: plain transpose B->A
//   RY qubits 6..11  (reg-local in frame A, packed-f32 VALU)
// LDS staging in fp16 RTNE. All DS intra-wave (private region, DS in-order).
// NOTE: no __launch_bounds__ 2nd arg — R3 showed it forces VGPR=64 + spills.
// ---------------------------------------------------------------------------

typedef __attribute__((ext_vector_type(8))) unsigned short ushort8;  // 16 B
typedef __attribute__((ext_vector_type(2))) float float2v;

__device__ constexpr int hfun(int r) {  // src lane for RT1 output reg r (CNOT index map)
    const int rb5 = (r >> 5) & 1, rb4 = (r >> 4) & 1, rb3 = (r >> 3) & 1;
    const int rb2 = (r >> 2) & 1, rb1 = (r >> 1) & 1, rb0 = r & 1;
    const int c0 = rb5;
    const int c1 = rb4 ^ rb5;
    const int c2 = rb3 ^ rb4;
    const int c3 = rb2 ^ rb3 ^ rb4;
    const int c4 = rb1 ^ rb2;
    const int c5 = rb0 ^ rb1 ^ rb2;
    return (c0 << 5) | (c1 << 4) | (c2 << 3) | (c3 << 2) | (c4 << 1) | c5;
}

// RY pair rotation over reg bit mask M, written as float2 math so LLVM can
// emit v_pk_mul_f32 / v_pk_fma_f32 (2 instrs per 2 outputs).
template <int M>
__device__ __forceinline__ void ry_local(float (&v)[64], float cw, float sw) {
    if (M >= 2) {
#pragma unroll
        for (int r = 0; r < 64; r += 2) {
            if (r & M) continue;
            const int r1 = r | M;
            float2v A = {v[r], v[r + 1]};
            float2v B = {v[r1], v[r1 + 1]};
            float2v lo = cw * A - sw * B;
            float2v hi = sw * A + cw * B;
            v[r] = lo.x;  v[r + 1] = lo.y;
            v[r1] = hi.x; v[r1 + 1] = hi.y;
        }
    } else {
        const float2v C1 = {cw, sw}, C2 = {-sw, cw};
#pragma unroll
        for (int r = 0; r < 64; r += 2) {
            float2v res = C1 * v[r] + C2 * v[r + 1];
            v[r] = res.x; v[r + 1] = res.y;
        }
    }
}

__global__ __launch_bounds__(WPB * 64) void vqc_kernel(const float* __restrict__ X,
                                                       const float* __restrict__ W,
                                                       float* __restrict__ out) {
    __shared__ __align__(16) unsigned short lds[WPB * 64 * LSTRIDE_H];

    const int lane   = threadIdx.x & 63;
    const int wid    = threadIdx.x >> 6;
    const int sample = blockIdx.x * WPB + wid;
    const int l      = lane;

    unsigned short* Wb   = &lds[wid * 64 * LSTRIDE_H];
    unsigned short* wrow = &Wb[l * LSTRIDE_H];        // row-major write base (16B aligned)
    const int G = l ^ (l >> 1) ^ ((l >> 2) & 5);      // src col l-part for RT1 (lane-local CNOTs)
    const unsigned short* rG0 = &Wb[G];               // r even (q5=0)
    const unsigned short* rG1 = &Wb[G ^ 0x30];        // r odd  (q5=1): CNOT(5,6) column flip
    const unsigned short* rT2 = &Wb[l];               // RT2 read base

    // ---- data encoding: product state, frame A ----
    float cx[NQ], sx[NQ];
#pragma unroll
    for (int q = 0; q < NQ; ++q) {
        float ang = 0.5f * X[sample * NQ + q] + 0.78539816339744831f;
        __sincosf(ang, &sx[q], &cx[q]);
    }
    float P = 1.0f;
#pragma unroll
    for (int q = 0; q < 6; ++q) P *= ((l >> (5 - q)) & 1) ? sx[q] : cx[q];

    float v[64];
    v[0] = P * cx[11];
    v[1] = P * sx[11];
#pragma unroll
    for (int lvl = 1; lvl < 6; ++lvl) {
        const int q = 11 - lvl;
#pragma unroll
        for (int j = 0; j < (1 << 5); ++j) {
            if (j >= (1 << lvl)) continue;
            v[j + (1 << lvl)] = v[j] * sx[q];
            v[j]              = v[j] * cx[q];
        }
    }

    // ---- variational layers ----
#pragma unroll 1
    for (int k = 0; k < DEPTH; ++k) {
        float cw[NQ], sw[NQ];
#pragma unroll
        for (int q = 0; q < NQ; ++q)
            __sincosf(0.5f * W[k * NQ + q], &sw[q], &cw[q]);

        // ---- RT1: frame A -> frame B with both CNOT groups folded (fp16 staging) ----
#pragma unroll
        for (int t = 0; t < 8; ++t) {
            ushort8 w;
#pragma unroll
            for (int i = 0; i < 8; ++i)
                w[i] = __half_as_ushort(__float2half(v[8 * t + i]));   // RTNE
            *(ushort8*)&wrow[8 * t] = w;
        }
#pragma unroll
        for (int r = 0; r < 64; ++r)
            v[r] = __half2float(__ushort_as_half(((r & 1) ? rG1 : rG0)[hfun(r) * LSTRIDE_H]));

        // ---- RY qubits 0..5 (frame B: qubit p <-> reg bit 5-p) ----
        ry_local<32>(v, cw[0], sw[0]);
        ry_local<16>(v, cw[1], sw[1]);
        ry_local<8>(v, cw[2], sw[2]);
        ry_local<4>(v, cw[3], sw[3]);
        ry_local<2>(v, cw[4], sw[4]);
        ry_local<1>(v, cw[5], sw[5]);

        // ---- RT2: plain transpose, frame B -> frame A (fp16 staging) ----
#pragma unroll
        for (int t = 0; t < 8; ++t) {
            ushort8 w;
#pragma unroll
            for (int i = 0; i < 8; ++i)
                w[i] = __half_as_ushort(__float2half(v[8 * t + i]));   // RTNE
            *(ushort8*)&wrow[8 * t] = w;
        }
#pragma unroll
        for (int j = 0; j < 64; ++j)
            v[j] = __half2float(__ushort_as_half(rT2[j * LSTRIDE_H]));

        // ---- RY qubits 6..11 (frame A: qubit p <-> reg bit 11-p) ----
        ry_local<32>(v, cw[6], sw[6]);
        ry_local<16>(v, cw[7], sw[7]);
        ry_local<8>(v, cw[8], sw[8]);
        ry_local<4>(v, cw[9], sw[9]);
        ry_local<2>(v, cw[10], sw[10]);
        ry_local<1>(v, cw[11], sw[11]);
    }

    // ---- measurement: <Z_p> = P(bit p = 0) - P(bit p = 1), frame A ----
#pragma unroll
    for (int j = 0; j < 64; ++j) v[j] *= v[j];

    float c2[16];  // summed over reg bits 0,1
#pragma unroll
    for (int m = 0; m < 16; ++m)
        c2[m] = (v[4 * m] + v[4 * m + 1]) + (v[4 * m + 2] + v[4 * m + 3]);

    float S = 0.0f;
#pragma unroll
    for (int m = 0; m < 16; ++m) S += c2[m];

    float T[4];  // signed sum on reg bit t+2
#pragma unroll
    for (int t = 0; t < 4; ++t) {
        float acc = 0.0f;
#pragma unroll
        for (int m = 0; m < 16; ++m) acc += ((m >> t) & 1) ? -c2[m] : c2[m];
        T[t] = acc;
    }

    float o[NCLASS];
#pragma unroll
    for (int p = 0; p < 6; ++p) {   // qubit p on lane bit (5-p)
        float r = ((l >> (5 - p)) & 1) ? -S : S;
#pragma unroll
        for (int m = 0; m < 6; ++m) r += __shfl_xor(r, 1 << m, 64);
        o[p] = r;
    }
#pragma unroll
    for (int p = 6; p < 10; ++p) {  // qubit p on reg bit (11-p) -> T[9-p]
        float r = T[9 - p];
#pragma unroll
        for (int m = 0; m < 6; ++m) r += __shfl_xor(r, 1 << m, 64);
        o[p] = r;
    }

    if (lane == 0) {
#pragma unroll
        for (int p = 0; p < NCLASS; ++p) out[sample * NCLASS + p] = o[p];
    }
}

extern "C" void kernel_launch(void* const* d_in, const int* in_sizes, int n_in,
                              void* d_out, int out_size, void* d_ws, size_t ws_size,
                              hipStream_t stream) {
    const float* X = (const float*)d_in[0];
    const float* W = (const float*)d_in[1];
    float* out     = (float*)d_out;
    (void)in_sizes; (void)n_in; (void)out_size; (void)d_ws; (void)ws_size;

    dim3 grid(BATCH / WPB);
    dim3 block(WPB * 64);
    hipLaunchKernelGGL(vqc_kernel, grid, block, 0, stream, X, W, out);
}